// Round 9
// baseline (2405.329 us; speedup 1.0000x reference)
//
#include <hip/hip_runtime.h>
#include <hip/hip_bf16.h>
#include <math.h>

#define S_DIM 128
#define H_DIM 256
#define A_DIM 8
#define T_STEPS 16
#define BT 8                // batch elems per block (main)
#define EPS_BAND 2e-4f

typedef __attribute__((ext_vector_type(8))) short short8;
typedef __attribute__((ext_vector_type(8))) unsigned short ushort8;
typedef __attribute__((ext_vector_type(4))) float f32x4;

__device__ inline unsigned short f32_to_bf16_rn(float f) {
    unsigned int u = __float_as_uint(f);
    return (unsigned short)((u + 0x7FFFu + ((u >> 16) & 1u)) >> 16);
}
__device__ inline float bf16_bits_to_f32(unsigned short b) {
    return __uint_as_float(((unsigned int)b) << 16);
}

// ============ main: time-batched MFMA (A = S1 [16t x 256j]) ==================
// 512 thr = 8 waves; wave w owns neurons m = w*32..w*32+31 (B-frags in regs).
// L1 exact: h1 f64 once -> 16-bit spike pattern per (b,n) in LDS.
// Per batch-pair: build A-tiles fragment-major (stride-1 LDS, conflict-free),
// one 16x256x256 GEMM (hi+mid bf16) per b, wave-local transpose, then the v2
// recursion runs 64 independent (b,m) chains per wave. u = sum_t 2^(t-16) s2.
__global__ __launch_bounds__(512, 2)
void snn_tmfma(const float* __restrict__ state,
               const float* __restrict__ W1, const float* __restrict__ b1,
               const float* __restrict__ W2, const float* __restrict__ b2,
               const float* __restrict__ W3, const float* __restrict__ b3,
               float* __restrict__ out,
               unsigned int* __restrict__ gcount, unsigned int* __restrict__ glist,
               unsigned int listcap)
{
    __shared__ float st_u[BT * 260];            // state [8][128] -> u [8][260]
    __shared__ unsigned short pat[BT * 256];    // L1 spike patterns
    __shared__ unsigned short atile[2][4096];   // A-tiles, fragment-major, 2 b's
    __shared__ float tbuf[8][2 * 512];          // per-wave transpose [2b][16t][32m]
    __shared__ float w3s[A_DIM * 260];
    __shared__ unsigned int flagw;

    const int tid = threadIdx.x;
    const int l = tid & 63, w = tid >> 6;
    const int cl = l & 15, c8 = l >> 4;
    const long b0 = (long)blockIdx.x * BT;

    if (tid == 0) flagw = 0;

    // ---- stage state [8][128] (256 float4) ----
    if (tid < 256)
        reinterpret_cast<float4*>(st_u)[tid] =
            reinterpret_cast<const float4*>(state + b0 * S_DIM)[tid];
    // ---- stage W3 [8][260] ----
    {
        const int a = tid >> 6, c = tid & 63;
        const float4 v = reinterpret_cast<const float4*>(W3)[tid];
        *reinterpret_cast<float4*>(&w3s[a * 260 + c * 4]) = v;
    }

    // ---- W2 B-frags (hi/mid bf16 split), register-resident ----
    short8 bhi[2][8], bmid[2][8];
    #pragma unroll
    for (int nt = 0; nt < 2; ++nt) {
        const int n = w * 32 + nt * 16 + cl;
        #pragma unroll
        for (int ks = 0; ks < 8; ++ks) {
            const float* src = W2 + n * H_DIM + ks * 32 + c8 * 8;
            const float4 a0 = *reinterpret_cast<const float4*>(src);
            const float4 a1 = *reinterpret_cast<const float4*>(src + 4);
            const float wv[8] = {a0.x, a0.y, a0.z, a0.w, a1.x, a1.y, a1.z, a1.w};
            short8 hi8, mi8;
            #pragma unroll
            for (int e = 0; e < 8; ++e) {
                const unsigned short hb = f32_to_bf16_rn(wv[e]);
                const float rem = wv[e] - bf16_bits_to_f32(hb);
                hi8[e] = (short)hb;
                mi8[e] = (short)f32_to_bf16_rn(rem);
            }
            bhi[nt][ks] = hi8;
            bmid[nt][ks] = mi8;
        }
    }
    const float b2r = b2[w * 32 + (l & 31)];
    __syncthreads();

    // ---- h1 exact f64 + L1 pattern (thread: neuron n1 x 4 b's) ----
    {
        const int n1 = tid & 255, bh = tid >> 8;
        double acc[4] = {0.0, 0.0, 0.0, 0.0};
        const float* w1p = W1 + n1 * S_DIM;
        #pragma unroll 4
        for (int kq = 0; kq < 32; ++kq) {
            const float4 w4 = reinterpret_cast<const float4*>(w1p)[kq];
            const double wd0 = (double)w4.x, wd1 = (double)w4.y;
            const double wd2 = (double)w4.z, wd3 = (double)w4.w;
            #pragma unroll
            for (int b4 = 0; b4 < 4; ++b4) {
                const float4 s4 = *reinterpret_cast<const float4*>(
                    &st_u[(bh * 4 + b4) * S_DIM + kq * 4]);
                double a = acc[b4];
                a = fma(wd0, (double)s4.x, a);
                a = fma(wd1, (double)s4.y, a);
                a = fma(wd2, (double)s4.z, a);
                a = fma(wd3, (double)s4.w, a);
                acc[b4] = a;
            }
        }
        const double b1d = (double)b1[n1];
        #pragma unroll
        for (int b4 = 0; b4 < 4; ++b4) {
            const double h1 = acc[b4] + b1d;
            double v = 0.0;
            unsigned int p = 0;
            #pragma unroll
            for (int t = 0; t < T_STEPS; ++t) {
                v = v + (h1 - v) * 0.5;
                if (v >= 1.0) { p |= (1u << t); v = 0.0; }
            }
            pat[(bh * 4 + b4) * 256 + n1] = (unsigned short)p;
        }
    }
    __syncthreads();

    // ---- pair loop: 2 batch elems per iteration ----
    #pragma unroll 1
    for (int p2 = 0; p2 < 4; ++p2) {
        // build A-tiles fragment-major: thread builds frag (ks=w, lane=l)
        {
            const int t = l & 15, jq = l >> 4;
            #pragma unroll
            for (int bb = 0; bb < 2; ++bb) {
                const int b = 2 * p2 + bb;
                const ushort8 p8 = *reinterpret_cast<const ushort8*>(
                    &pat[b * 256 + w * 32 + jq * 8]);
                short8 af;
                #pragma unroll
                for (int e = 0; e < 8; ++e)
                    af[e] = (short)((((unsigned int)p8[e] >> t) & 1u) ? 0x3F80 : 0);
                *reinterpret_cast<short8*>(&atile[bb][(w * 64 + l) * 8]) = af;
            }
        }
        __syncthreads();

        // GEMM: [16t x 256j] @ W2^T(hi+mid) for both b's of the pair
        f32x4 a00 = {0, 0, 0, 0}, a01 = {0, 0, 0, 0};
        f32x4 a10 = {0, 0, 0, 0}, a11 = {0, 0, 0, 0};
        #pragma unroll
        for (int ks = 0; ks < 8; ++ks) {
            const short8 af0 = *reinterpret_cast<const short8*>(&atile[0][(ks * 64 + l) * 8]);
            const short8 af1 = *reinterpret_cast<const short8*>(&atile[1][(ks * 64 + l) * 8]);
            a00 = __builtin_amdgcn_mfma_f32_16x16x32_bf16(af0, bhi[0][ks], a00, 0, 0, 0);
            a00 = __builtin_amdgcn_mfma_f32_16x16x32_bf16(af0, bmid[0][ks], a00, 0, 0, 0);
            a01 = __builtin_amdgcn_mfma_f32_16x16x32_bf16(af0, bhi[1][ks], a01, 0, 0, 0);
            a01 = __builtin_amdgcn_mfma_f32_16x16x32_bf16(af0, bmid[1][ks], a01, 0, 0, 0);
            a10 = __builtin_amdgcn_mfma_f32_16x16x32_bf16(af1, bhi[0][ks], a10, 0, 0, 0);
            a10 = __builtin_amdgcn_mfma_f32_16x16x32_bf16(af1, bmid[0][ks], a10, 0, 0, 0);
            a11 = __builtin_amdgcn_mfma_f32_16x16x32_bf16(af1, bhi[1][ks], a11, 0, 0, 0);
            a11 = __builtin_amdgcn_mfma_f32_16x16x32_bf16(af1, bmid[1][ks], a11, 0, 0, 0);
        }

        // wave-local transpose: C(row=t=4c8+r, col=m) -> tbuf[bb][t][swz(m,t)]
        {
            float* tb = tbuf[w];
            #pragma unroll
            for (int r = 0; r < 4; ++r) {
                const int t = 4 * c8 + r;
                tb[t * 32 + ((cl + 2 * t) & 31)]            = a00[r];
                tb[t * 32 + ((16 + cl + 2 * t) & 31)]      = a01[r];
                tb[512 + t * 32 + ((cl + 2 * t) & 31)]     = a10[r];
                tb[512 + t * 32 + ((16 + cl + 2 * t) & 31)] = a11[r];
            }
        }
        // v2 recursion: lane owns chain (b = 2*p2 + (l>>5), m = l&31)
        {
            const int rm = l & 31, rbb = l >> 5;
            const float* tb = tbuf[w] + rbb * 512;
            float v2 = 0.0f, u = 0.0f, ct = 0x1p-16f;
            unsigned int fl = 0;
            #pragma unroll
            for (int t = 0; t < T_STEPS; ++t) {
                const float h2 = tb[t * 32 + ((rm + 2 * t) & 31)] + b2r;
                const float v = (v2 + h2) * 0.5f;
                if (fabsf(v - 1.0f) < EPS_BAND) fl = 1u;
                const bool sp = v >= 1.0f;
                v2 = sp ? 0.0f : v;
                u += sp ? ct : 0.0f;
                ct *= 2.0f;
            }
            const int b = 2 * p2 + rbb;
            st_u[b * 260 + w * 32 + rm] = u;
            if (fl) atomicOr(&flagw, 1u << b);
        }
        __syncthreads();
    }

    // ---- epilogue: out = tanh(u @ W3^T + b3*(1-2^-16)) (R8-identical math) ----
    if (tid < BT * A_DIM) {
        const int b = tid >> 3, a = tid & 7;
        float s0 = 0, s1v = 0, s2v = 0, s3 = 0;
        #pragma unroll 8
        for (int kq = 0; kq < 64; ++kq) {
            const float4 uv = *reinterpret_cast<const float4*>(&st_u[b * 260 + kq * 4]);
            const float4 wv = *reinterpret_cast<const float4*>(&w3s[a * 260 + kq * 4]);
            s0 = fmaf(uv.x, wv.x, s0);
            s1v = fmaf(uv.y, wv.y, s1v);
            s2v = fmaf(uv.z, wv.z, s2v);
            s3 = fmaf(uv.w, wv.w, s3);
        }
        const float v3 = (s0 + s1v) + (s2v + s3) + b3[a] * (1.0f - 0x1p-16f);
        out[(b0 + b) * A_DIM + a] = tanhf(v3);
    }

    // ---- append flagged batch elems ----
    if (tid < BT) {
        if ((flagw >> tid) & 1u) {
            const unsigned int idx = atomicAdd(gcount, 1u);
            if (idx < listcap) glist[idx] = (unsigned int)(b0 + tid);
        }
    }
}

// ================ fixup: exact f64 re-sim of flagged elems (R8 verbatim) =====
__global__ __launch_bounds__(512, 2)
void snn_fix(const float* __restrict__ state,
             const float* __restrict__ W1, const float* __restrict__ b1,
             const float* __restrict__ W2, const float* __restrict__ b2,
             const float* __restrict__ W3, const float* __restrict__ b3,
             float* __restrict__ out,
             const unsigned int* __restrict__ gcount,
             const unsigned int* __restrict__ glist,
             unsigned int listcap)
{
    __shared__ float  s1s[H_DIM];
    __shared__ double redh[H_DIM];
    __shared__ double uu[H_DIM];

    const int tid = threadIdx.x;
    const int n = tid & 255;
    const int kh = tid >> 8;
    unsigned int cnt = *gcount;
    if (cnt > listcap) cnt = listcap;
    if (cnt == 0) return;

    float4 w2f[32];
    #pragma unroll
    for (int q = 0; q < 32; ++q)
        w2f[q] = reinterpret_cast<const float4*>(W2 + n * H_DIM + kh * 128)[q];

    const double b1d = (double)b1[n];
    const double b2d = (double)b2[n];

    for (unsigned int i = blockIdx.x; i < cnt; i += gridDim.x) {
        const long be = (long)glist[i];

        double hp = 0.0;
        {
            const float* w1p = W1 + n * S_DIM + kh * 64;
            const float* stp = state + be * S_DIM + kh * 64;
            #pragma unroll
            for (int kq = 0; kq < 16; ++kq) {
                const float4 w4 = reinterpret_cast<const float4*>(w1p)[kq];
                const float4 s4 = reinterpret_cast<const float4*>(stp)[kq];
                hp = fma((double)w4.x, (double)s4.x, hp);
                hp = fma((double)w4.y, (double)s4.y, hp);
                hp = fma((double)w4.z, (double)s4.z, hp);
                hp = fma((double)w4.w, (double)s4.w, hp);
            }
        }
        if (kh) redh[n] = hp;
        __syncthreads();
        double h1 = 0.0, v1 = 0.0, v2 = 0.0, un = 0.0;
        if (!kh) h1 = hp + redh[n] + b1d;
        double ct = 0x1p-16;

        for (int t = 0; t < T_STEPS; ++t) {
            if (!kh) {
                v1 = v1 + (h1 - v1) * 0.5;
                const bool sp = (v1 >= 1.0);
                v1 = sp ? 0.0 : v1;
                s1s[n] = sp ? 1.0f : 0.0f;
            }
            __syncthreads();
            double h2p = 0.0;
            #pragma unroll
            for (int q = 0; q < 32; ++q) {
                const float4 w4 = w2f[q];
                const float4 s4 = *reinterpret_cast<const float4*>(&s1s[kh * 128 + q * 4]);
                h2p = fma((double)w4.x, (double)s4.x, h2p);
                h2p = fma((double)w4.y, (double)s4.y, h2p);
                h2p = fma((double)w4.z, (double)s4.z, h2p);
                h2p = fma((double)w4.w, (double)s4.w, h2p);
            }
            __syncthreads();
            if (kh) redh[n] = h2p;
            __syncthreads();
            if (!kh) {
                const double h2 = h2p + redh[n] + b2d;
                v2 = v2 + (h2 - v2) * 0.5;
                const bool sp = (v2 >= 1.0);
                v2 = sp ? 0.0 : v2;
                un += sp ? ct : 0.0;
            }
            ct *= 2.0;
        }
        if (!kh) uu[n] = un;
        __syncthreads();
        if (tid < A_DIM) {
            double d0 = 0, d1 = 0, d2 = 0, d3 = 0;
            const float* w3p = W3 + tid * H_DIM;
            for (int j = 0; j < H_DIM; j += 4) {
                d0 = fma((double)w3p[j],     uu[j],     d0);
                d1 = fma((double)w3p[j + 1], uu[j + 1], d1);
                d2 = fma((double)w3p[j + 2], uu[j + 2], d2);
                d3 = fma((double)w3p[j + 3], uu[j + 3], d3);
            }
            const double v3 = (d0 + d1) + (d2 + d3) + (double)b3[tid] * (1.0 - 0x1p-16);
            out[be * A_DIM + tid] = (float)tanh(v3);
        }
        __syncthreads();
    }
}

extern "C" void kernel_launch(void* const* d_in, const int* in_sizes, int n_in,
                              void* d_out, int out_size, void* d_ws, size_t ws_size,
                              hipStream_t stream)
{
    const float* state = (const float*)d_in[0];
    const float* W1    = (const float*)d_in[1];
    const float* b1    = (const float*)d_in[2];
    const float* W2    = (const float*)d_in[3];
    const float* b2    = (const float*)d_in[4];
    const float* W3    = (const float*)d_in[5];
    const float* b3    = (const float*)d_in[6];
    float* out = (float*)d_out;

    unsigned int* gcount = (unsigned int*)d_ws;
    unsigned int* glist  = (unsigned int*)d_ws + 4;
    const unsigned int listcap =
        (ws_size > 64) ? (unsigned int)((ws_size - 16) / 4) : 0;

    hipMemsetAsync(d_ws, 0, 16, stream);   // zero flag counter (stream-ordered)

    const int B = in_sizes[0] / S_DIM;     // 131072

    snn_tmfma<<<B / BT, 512, 0, stream>>>(state, W1, b1, W2, b2, W3, b3,
                                          out, gcount, glist, listcap);
    snn_fix<<<2048, 512, 0, stream>>>(state, W1, b1, W2, b2, W3, b3,
                                      out, gcount, glist, listcap);
}

// Round 10
// 1623.827 us; speedup vs baseline: 1.4813x; 1.4813x over previous
//
#include <hip/hip_runtime.h>
#include <hip/hip_bf16.h>
#include <math.h>

#define S_DIM 128
#define H_DIM 256
#define A_DIM 8
#define T_STEPS 16
#define BT 8                // batch elems per iteration
#define EPS_BAND 2e-4f
#define TS 18               // tbuf row stride in f32 (2-way/4-way bank-clean, b64-aligned)

typedef __attribute__((ext_vector_type(8))) short short8;
typedef __attribute__((ext_vector_type(8))) unsigned short ushort8;
typedef __attribute__((ext_vector_type(4))) float f32x4;

__device__ inline unsigned short f32_to_bf16_rn(float f) {
    unsigned int u = __float_as_uint(f);
    return (unsigned short)((u + 0x7FFFu + ((u >> 16) & 1u)) >> 16);
}
__device__ inline float bf16_bits_to_f32(unsigned short b) {
    return __uint_as_float(((unsigned int)b) << 16);
}

// exact f64 h1 + 16-step L1 recursion -> 16-bit spike pattern per (b,n).
// thread handles neuron n1 for 4 batch elems (bh selects which half).
__device__ __forceinline__ void make_pat(
    const float* __restrict__ state, const float* __restrict__ W1,
    double b1d, int n1, int bh, long bset, unsigned short* __restrict__ patdst)
{
    double acc[4] = {0.0, 0.0, 0.0, 0.0};
    const float4* w1p = reinterpret_cast<const float4*>(W1 + n1 * S_DIM);
    const float4* sp  = reinterpret_cast<const float4*>(state + (bset * BT + bh * 4) * S_DIM);
    #pragma unroll 4
    for (int kq = 0; kq < 32; ++kq) {
        const float4 w4 = w1p[kq];
        const double wd0 = (double)w4.x, wd1 = (double)w4.y;
        const double wd2 = (double)w4.z, wd3 = (double)w4.w;
        #pragma unroll
        for (int b4 = 0; b4 < 4; ++b4) {
            const float4 s4 = sp[b4 * 32 + kq];
            double a = acc[b4];
            a = fma(wd0, (double)s4.x, a);
            a = fma(wd1, (double)s4.y, a);
            a = fma(wd2, (double)s4.z, a);
            a = fma(wd3, (double)s4.w, a);
            acc[b4] = a;
        }
    }
    #pragma unroll
    for (int b4 = 0; b4 < 4; ++b4) {
        const double h1 = acc[b4] + b1d;
        double v = 0.0;
        unsigned int p = 0;
        #pragma unroll
        for (int t = 0; t < T_STEPS; ++t) {
            v = v + (h1 - v) * 0.5;
            if (v >= 1.0) { p |= (1u << t); v = 0.0; }
        }
        patdst[(bh * 4 + b4) * 256 + n1] = (unsigned short)p;
    }
}

// =========== persistent main: 256 blocks x 64 iterations of 8 batch elems ====
// 8 waves; wave w owns neurons w*32..w*32+31 (W2 hi/mid bf16 frags in regs).
// Per iter: build 8 A-tiles [16t x 256j] fragment-major -> barrier ->
// 4 pair-GEMMs + wave-local transpose + in-reg v2 recursion (no barriers) ->
// f64 patterns for NEXT iter (overlaps on VALU/VMEM pipes) -> barrier ->
// epilogue u@W3 + tanh. Flag band 2e-4 -> f64 fixup kernel.
__global__ __launch_bounds__(512, 2)
void snn_pers(const float* __restrict__ state,
              const float* __restrict__ W1, const float* __restrict__ b1,
              const float* __restrict__ W2, const float* __restrict__ b2,
              const float* __restrict__ W3, const float* __restrict__ b3,
              float* __restrict__ out,
              unsigned int* __restrict__ gcount, unsigned int* __restrict__ glist,
              unsigned int listcap, int nIter)
{
    __shared__ unsigned short atile[8 * 4096];     // 64 KB  A-tiles (frag-major)
    __shared__ unsigned short pat[2][8 * 256];     // 8 KB   L1 patterns (dbuf)
    __shared__ float tbuf[8][64 * TS];             // 36 KB  per-wave transpose
    __shared__ float st_u[8 * 260];                // 8.3 KB u vectors
    __shared__ float w3s[A_DIM * 260];             // 8.3 KB W3 staged
    __shared__ float red3[8][64];                  // 2 KB   epilogue partials
    __shared__ unsigned int flagw;

    const int tid = threadIdx.x;
    const int l = tid & 63, w = tid >> 6;
    const int cl = l & 15, c8 = l >> 4;

    if (tid == 0) flagw = 0;

    // ---- stage W3 [8][260] ----
    {
        const int a = tid >> 6, c = tid & 63;
        const float4 v = reinterpret_cast<const float4*>(W3)[tid];
        *reinterpret_cast<float4*>(&w3s[a * 260 + c * 4]) = v;
    }

    // ---- W2 hi/mid bf16 fragments, register-resident (built once) ----
    short8 bhi[2][8], bmid[2][8];
    #pragma unroll
    for (int nt = 0; nt < 2; ++nt) {
        const int n = w * 32 + nt * 16 + cl;
        #pragma unroll
        for (int ks = 0; ks < 8; ++ks) {
            const float* src = W2 + n * H_DIM + ks * 32 + c8 * 8;
            const float4 a0 = *reinterpret_cast<const float4*>(src);
            const float4 a1 = *reinterpret_cast<const float4*>(src + 4);
            const float wv[8] = {a0.x, a0.y, a0.z, a0.w, a1.x, a1.y, a1.z, a1.w};
            short8 hi8, mi8;
            #pragma unroll
            for (int e = 0; e < 8; ++e) {
                const unsigned short hb = f32_to_bf16_rn(wv[e]);
                const float rem = wv[e] - bf16_bits_to_f32(hb);
                hi8[e] = (short)hb;
                mi8[e] = (short)f32_to_bf16_rn(rem);
            }
            bhi[nt][ks] = hi8;
            bmid[nt][ks] = mi8;
        }
    }
    const float b2r = b2[w * 32 + (l & 31)];
    const int n1 = tid & 255, bh = tid >> 8;
    const double b1d = (double)b1[n1];

    const long bsetBase = (long)blockIdx.x * nIter;

    // patterns for iteration 0
    make_pat(state, W1, b1d, n1, bh, bsetBase, &pat[0][0]);
    __syncthreads();

    #pragma unroll 1
    for (int it = 0; it < nIter; ++it) {
        const int cur = it & 1;
        const long b0 = (bsetBase + it) * BT;

        // ---- build A-tiles: thread = frag (ks=w, lane=l) for each b ----
        {
            const int jb = w * 32 + c8 * 8;
            #pragma unroll
            for (int b = 0; b < 8; ++b) {
                const ushort8 p8 = *reinterpret_cast<const ushort8*>(&pat[cur][b * 256 + jb]);
                short8 af;
                #pragma unroll
                for (int e = 0; e < 8; ++e)
                    af[e] = (short)((((unsigned int)p8[e] >> cl) & 1u) ? 0x3F80 : 0);
                *reinterpret_cast<short8*>(&atile[b * 4096 + tid * 8]) = af;
            }
        }
        __syncthreads();   // [A] tiles ready

        // ---- 4 batch-pairs: GEMM + transpose + recursion (no barriers) ----
        #pragma unroll 1
        for (int p2 = 0; p2 < 4; ++p2) {
            f32x4 c0 = {0,0,0,0}, c1 = {0,0,0,0}, c2 = {0,0,0,0}, c3 = {0,0,0,0};
            f32x4 c4 = {0,0,0,0}, c5 = {0,0,0,0}, c6 = {0,0,0,0}, c7 = {0,0,0,0};
            #pragma unroll
            for (int ks = 0; ks < 8; ++ks) {
                const short8 af0 = *reinterpret_cast<const short8*>(
                    &atile[(2 * p2) * 4096 + (ks * 64 + l) * 8]);
                const short8 af1 = *reinterpret_cast<const short8*>(
                    &atile[(2 * p2 + 1) * 4096 + (ks * 64 + l) * 8]);
                c0 = __builtin_amdgcn_mfma_f32_16x16x32_bf16(af0, bhi[0][ks],  c0, 0, 0, 0);
                c1 = __builtin_amdgcn_mfma_f32_16x16x32_bf16(af0, bmid[0][ks], c1, 0, 0, 0);
                c2 = __builtin_amdgcn_mfma_f32_16x16x32_bf16(af0, bhi[1][ks],  c2, 0, 0, 0);
                c3 = __builtin_amdgcn_mfma_f32_16x16x32_bf16(af0, bmid[1][ks], c3, 0, 0, 0);
                c4 = __builtin_amdgcn_mfma_f32_16x16x32_bf16(af1, bhi[0][ks],  c4, 0, 0, 0);
                c5 = __builtin_amdgcn_mfma_f32_16x16x32_bf16(af1, bmid[0][ks], c5, 0, 0, 0);
                c6 = __builtin_amdgcn_mfma_f32_16x16x32_bf16(af1, bhi[1][ks],  c6, 0, 0, 0);
                c7 = __builtin_amdgcn_mfma_f32_16x16x32_bf16(af1, bmid[1][ks], c7, 0, 0, 0);
            }
            const f32x4 a00 = c0 + c1, a01 = c2 + c3, a10 = c4 + c5, a11 = c6 + c7;

            // wave-local transpose: C[t=4c8+r][n] -> tbuf rows (n-chain), cols t
            float* tb = &tbuf[w][0];
            const int col = 4 * c8;
            *reinterpret_cast<float2*>(&tb[cl * TS + col])            = make_float2(a00[0], a00[1]);
            *reinterpret_cast<float2*>(&tb[cl * TS + col + 2])        = make_float2(a00[2], a00[3]);
            *reinterpret_cast<float2*>(&tb[(16 + cl) * TS + col])     = make_float2(a01[0], a01[1]);
            *reinterpret_cast<float2*>(&tb[(16 + cl) * TS + col + 2]) = make_float2(a01[2], a01[3]);
            *reinterpret_cast<float2*>(&tb[(32 + cl) * TS + col])     = make_float2(a10[0], a10[1]);
            *reinterpret_cast<float2*>(&tb[(32 + cl) * TS + col + 2]) = make_float2(a10[2], a10[3]);
            *reinterpret_cast<float2*>(&tb[(48 + cl) * TS + col])     = make_float2(a11[0], a11[1]);
            *reinterpret_cast<float2*>(&tb[(48 + cl) * TS + col + 2]) = make_float2(a11[2], a11[3]);

            // v2 recursion: lane owns chain (b = 2p2 + l>>5, n = w*32 + (l&31))
            {
                const int rm = l & 31, rbb = l >> 5;
                const float* tr = &tbuf[w][(rbb * 32 + rm) * TS];
                float v2 = 0.0f, vmin = 1e9f;
                unsigned int m = 0;
                #pragma unroll
                for (int g = 0; g < 8; ++g) {
                    const float2 h2 = *reinterpret_cast<const float2*>(&tr[g * 2]);
                    {
                        const float v = (v2 + (h2.x + b2r)) * 0.5f;
                        vmin = fminf(vmin, fabsf(v - 1.0f));
                        const bool sp = v >= 1.0f;
                        v2 = sp ? 0.0f : v;
                        m |= sp ? (1u << (2 * g)) : 0u;
                    }
                    {
                        const float v = (v2 + (h2.y + b2r)) * 0.5f;
                        vmin = fminf(vmin, fabsf(v - 1.0f));
                        const bool sp = v >= 1.0f;
                        v2 = sp ? 0.0f : v;
                        m |= sp ? (1u << (2 * g + 1)) : 0u;
                    }
                }
                const int b = 2 * p2 + rbb;
                st_u[b * 260 + w * 32 + rm] = (float)m * 0x1p-16f;
                if (vmin < EPS_BAND) atomicOr(&flagw, 1u << b);
            }
        }

        // ---- patterns for next iter (VALU/VMEM pipes; waves drift freely) ----
        if (it + 1 < nIter)
            make_pat(state, W1, b1d, n1, bh, bsetBase + it + 1, &pat[cur ^ 1][0]);

        __syncthreads();   // [B] st_u + flags + next-pat complete

        const unsigned int flcopy = (tid < BT) ? flagw : 0u;

        // ---- epilogue: out = tanh(u @ W3^T + b3*(1-2^-16)) ----
        {
            const int task = tid & 63, chunk = tid >> 6;
            const int b = task >> 3, a = task & 7;
            const int j0 = chunk * 32;
            float s0 = 0, s1v = 0, s2v = 0, s3 = 0;
            #pragma unroll
            for (int qq = 0; qq < 8; ++qq) {
                const float4 uv = *reinterpret_cast<const float4*>(&st_u[b * 260 + j0 + qq * 4]);
                const float4 wv = *reinterpret_cast<const float4*>(&w3s[a * 260 + j0 + qq * 4]);
                s0 = fmaf(uv.x, wv.x, s0);
                s1v = fmaf(uv.y, wv.y, s1v);
                s2v = fmaf(uv.z, wv.z, s2v);
                s3 = fmaf(uv.w, wv.w, s3);
            }
            red3[chunk][task] = (s0 + s1v) + (s2v + s3);
        }
        __syncthreads();   // [C]

        if (tid < 64) {
            const int a = tid & 7;
            const float h = ((red3[0][tid] + red3[1][tid]) + (red3[2][tid] + red3[3][tid]))
                          + ((red3[4][tid] + red3[5][tid]) + (red3[6][tid] + red3[7][tid]))
                          + b3[a] * (1.0f - 0x1p-16f);
            out[b0 * A_DIM + tid] = tanhf(h);
        }
        if (tid < BT && ((flcopy >> tid) & 1u)) {
            const unsigned int idx = atomicAdd(gcount, 1u);
            if (idx < listcap) glist[idx] = (unsigned int)(b0 + tid);
        }
        if (tid == 0) flagw = 0;   // next atomics are after barrier [A]
    }
}

// ================ fixup: exact f64 re-sim of flagged elems (validated) =======
__global__ __launch_bounds__(512, 2)
void snn_fix(const float* __restrict__ state,
             const float* __restrict__ W1, const float* __restrict__ b1,
             const float* __restrict__ W2, const float* __restrict__ b2,
             const float* __restrict__ W3, const float* __restrict__ b3,
             float* __restrict__ out,
             const unsigned int* __restrict__ gcount,
             const unsigned int* __restrict__ glist,
             unsigned int listcap)
{
    __shared__ float  s1s[H_DIM];
    __shared__ double redh[H_DIM];
    __shared__ double uu[H_DIM];

    const int tid = threadIdx.x;
    const int n = tid & 255;
    const int kh = tid >> 8;
    unsigned int cnt = *gcount;
    if (cnt > listcap) cnt = listcap;
    if (cnt == 0) return;

    float4 w2f[32];
    #pragma unroll
    for (int q = 0; q < 32; ++q)
        w2f[q] = reinterpret_cast<const float4*>(W2 + n * H_DIM + kh * 128)[q];

    const double b1d = (double)b1[n];
    const double b2d = (double)b2[n];

    for (unsigned int i = blockIdx.x; i < cnt; i += gridDim.x) {
        const long be = (long)glist[i];

        double hp = 0.0;
        {
            const float* w1p = W1 + n * S_DIM + kh * 64;
            const float* stp = state + be * S_DIM + kh * 64;
            #pragma unroll
            for (int kq = 0; kq < 16; ++kq) {
                const float4 w4 = reinterpret_cast<const float4*>(w1p)[kq];
                const float4 s4 = reinterpret_cast<const float4*>(stp)[kq];
                hp = fma((double)w4.x, (double)s4.x, hp);
                hp = fma((double)w4.y, (double)s4.y, hp);
                hp = fma((double)w4.z, (double)s4.z, hp);
                hp = fma((double)w4.w, (double)s4.w, hp);
            }
        }
        if (kh) redh[n] = hp;
        __syncthreads();
        double h1 = 0.0, v1 = 0.0, v2 = 0.0, un = 0.0;
        if (!kh) h1 = hp + redh[n] + b1d;
        double ct = 0x1p-16;

        for (int t = 0; t < T_STEPS; ++t) {
            if (!kh) {
                v1 = v1 + (h1 - v1) * 0.5;
                const bool sp = (v1 >= 1.0);
                v1 = sp ? 0.0 : v1;
                s1s[n] = sp ? 1.0f : 0.0f;
            }
            __syncthreads();
            double h2p = 0.0;
            #pragma unroll
            for (int q = 0; q < 32; ++q) {
                const float4 w4 = w2f[q];
                const float4 s4 = *reinterpret_cast<const float4*>(&s1s[kh * 128 + q * 4]);
                h2p = fma((double)w4.x, (double)s4.x, h2p);
                h2p = fma((double)w4.y, (double)s4.y, h2p);
                h2p = fma((double)w4.z, (double)s4.z, h2p);
                h2p = fma((double)w4.w, (double)s4.w, h2p);
            }
            __syncthreads();
            if (kh) redh[n] = h2p;
            __syncthreads();
            if (!kh) {
                const double h2 = h2p + redh[n] + b2d;
                v2 = v2 + (h2 - v2) * 0.5;
                const bool sp = (v2 >= 1.0);
                v2 = sp ? 0.0 : v2;
                un += sp ? ct : 0.0;
            }
            ct *= 2.0;
        }
        if (!kh) uu[n] = un;
        __syncthreads();
        if (tid < A_DIM) {
            double d0 = 0, d1 = 0, d2 = 0, d3 = 0;
            const float* w3p = W3 + tid * H_DIM;
            for (int j = 0; j < H_DIM; j += 4) {
                d0 = fma((double)w3p[j],     uu[j],     d0);
                d1 = fma((double)w3p[j + 1], uu[j + 1], d1);
                d2 = fma((double)w3p[j + 2], uu[j + 2], d2);
                d3 = fma((double)w3p[j + 3], uu[j + 3], d3);
            }
            const double v3 = (d0 + d1) + (d2 + d3) + (double)b3[tid] * (1.0 - 0x1p-16);
            out[be * A_DIM + tid] = (float)tanh(v3);
        }
        __syncthreads();
    }
}

extern "C" void kernel_launch(void* const* d_in, const int* in_sizes, int n_in,
                              void* d_out, int out_size, void* d_ws, size_t ws_size,
                              hipStream_t stream)
{
    const float* state = (const float*)d_in[0];
    const float* W1    = (const float*)d_in[1];
    const float* b1    = (const float*)d_in[2];
    const float* W2    = (const float*)d_in[3];
    const float* b2    = (const float*)d_in[4];
    const float* W3    = (const float*)d_in[5];
    const float* b3    = (const float*)d_in[6];
    float* out = (float*)d_out;

    unsigned int* gcount = (unsigned int*)d_ws;
    unsigned int* glist  = (unsigned int*)d_ws + 4;
    const unsigned int listcap =
        (ws_size > 64) ? (unsigned int)((ws_size - 16) / 4) : 0;

    hipMemsetAsync(d_ws, 0, 16, stream);   // zero flag counter (stream-ordered)

    const int B = in_sizes[0] / S_DIM;     // 131072
    const int GRID = 256;                  // persistent: 1 block per CU
    const int nIter = B / (GRID * BT);     // 64

    snn_pers<<<GRID, 512, 0, stream>>>(state, W1, b1, W2, b2, W3, b3,
                                       out, gcount, glist, listcap, nIter);
    snn_fix<<<2048, 512, 0, stream>>>(state, W1, b1, W2, b2, W3, b3,
                                      out, gcount, glist, listcap);
}